// Round 6
// baseline (27041.397 us; speedup 1.0000x reference)
//
#include <hip/hip_runtime.h>
#include <hip/hip_fp16.h>

#define TT 512
#define MM 512
#define NWG 256
#define NTHR 768

// ---------------- fast math ----------------
__device__ __forceinline__ float fast_sigmoid(float x) {
  float e = __expf(-x);
  return __builtin_amdgcn_rcpf(1.f + e);
}
__device__ __forceinline__ float fast_tanh(float x) {
  float e = __expf(2.f * x);
  return 1.f - 2.f * __builtin_amdgcn_rcpf(e + 1.f);
}
__device__ __forceinline__ float2 h2f2(unsigned u) {
  __half2 h = *reinterpret_cast<__half2*>(&u);
  return __half22float2(h);
}
__device__ __forceinline__ unsigned pack2(float x, float y) {
  __half2 h = __floats2half2_rn(x, y);
  return *reinterpret_cast<unsigned*>(&h);
}

typedef _Float16 hf2_t __attribute__((ext_vector_type(2)));
__device__ __forceinline__ float fdot2f(unsigned a, unsigned b, float c) {
#if __has_builtin(__builtin_amdgcn_fdot2)
  union U { unsigned u; hf2_t h; };
  U ua, ub; ua.u = a; ub.u = b;
  return __builtin_amdgcn_fdot2(ua.h, ub.h, c, false);
#else
  float2 fa = h2f2(a), fb = h2f2(b);
  return fmaf(fa.x, fb.x, fmaf(fa.y, fb.y, c));
#endif
}

// 24-deep software-pipelined dot: w strided by S (global), x2 in LDS. K%24==0.
template<int K, int S>
__device__ __forceinline__ float dotpipe(const unsigned* __restrict__ w,
                                         const unsigned* __restrict__ x2) {
  unsigned A[12], B[12];
  float acc[4] = {0.f, 0.f, 0.f, 0.f};
  #pragma unroll
  for (int i = 0; i < 12; ++i) A[i] = w[(size_t)i * S];
  #pragma unroll 1
  for (int k = 0; k < K; k += 24) {
    #pragma unroll
    for (int i = 0; i < 12; ++i) B[i] = w[(size_t)(k + 12 + i) * S];
    #pragma unroll
    for (int i = 0; i < 12; ++i) acc[i & 3] = fdot2f(A[i], x2[k + i], acc[i & 3]);
    if (k + 24 < K) {
      #pragma unroll
      for (int i = 0; i < 12; ++i) A[i] = w[(size_t)(k + 24 + i) * S];
    }
    #pragma unroll
    for (int i = 0; i < 12; ++i) acc[i & 3] = fdot2f(B[i], x2[k + 12 + i], acc[i & 3]);
  }
  return (acc[0] + acc[1]) + (acc[2] + acc[3]);
}

// ---------------- agent-scope atomics ----------------
__device__ __forceinline__ void ast(float* p, float v) {
  __hip_atomic_store(p, v, __ATOMIC_RELAXED, __HIP_MEMORY_SCOPE_AGENT);
}
__device__ __forceinline__ float ald(const float* p) {
  return __hip_atomic_load(p, __ATOMIC_RELAXED, __HIP_MEMORY_SCOPE_AGENT);
}
__device__ __forceinline__ void astu(unsigned* p, unsigned v) {
  __hip_atomic_store(p, v, __ATOMIC_RELAXED, __HIP_MEMORY_SCOPE_AGENT);
}
__device__ __forceinline__ unsigned aldu(const unsigned* p) {
  return __hip_atomic_load(p, __ATOMIC_RELAXED, __HIP_MEMORY_SCOPE_AGENT);
}
__device__ __forceinline__ void astull(unsigned long long* p, unsigned long long v) {
  __hip_atomic_store(p, v, __ATOMIC_RELAXED, __HIP_MEMORY_SCOPE_AGENT);
}
__device__ __forceinline__ unsigned long long aldull(const unsigned long long* p) {
  return __hip_atomic_load(p, __ATOMIC_RELAXED, __HIP_MEMORY_SCOPE_AGENT);
}
union F2U { unsigned long long u; float f[2]; };

// ---------------- precompute: proj (fp16 out; transp: 0=[r][a], 1=[b][m][a], 2=[b][a][m]) ----------------
struct ProjParams {
  const float* X[4]; const float* W[4]; __half* C[4]; int rev[4]; int transp[4];
};

__global__ __launch_bounds__(192) void proj_kernel(ProjParams pp) {
  __shared__ float xs[32 * 384];
  const int job = blockIdx.y;
  const float* __restrict__ X = pp.X[job];
  const float* __restrict__ W = pp.W[job];
  __half* __restrict__ C = pp.C[job];
  const int rev = pp.rev[job];
  const int transp = pp.transp[job];
  const int r0 = blockIdx.x * 32;
  const int tid = threadIdx.x;

  for (int idx = tid; idx < 32 * 384; idx += 192) {
    int r = idx / 384, k = idx - r * 384;
    int row = r0 + r;
    int srow = row;
    if (rev) { int t = row >> 6, b2 = row & 63; srow = ((TT - 1 - t) << 6) | b2; }
    xs[idx] = X[(size_t)srow * 384 + k];
  }
  __syncthreads();

  float acc[32];
  #pragma unroll
  for (int r = 0; r < 32; ++r) acc[r] = 0.f;
  for (int k = 0; k < 384; ++k) {
    float w = W[k * 192 + tid];
    #pragma unroll
    for (int r = 0; r < 32; ++r) acc[r] = fmaf(xs[r * 384 + k], w, acc[r]);
  }
  #pragma unroll
  for (int r = 0; r < 32; ++r) {
    int row = r0 + r;
    size_t di;
    if (transp == 2)      di = ((size_t)(row & 63) * 192 + tid) * 512 + (row >> 6);
    else if (transp == 1) di = ((size_t)(row & 63) * MM + (row >> 6)) * 192 + tid;
    else                  di = (size_t)row * 192 + tid;
    C[di] = __float2half(acc[r]);
  }
}

// memt[b][m][d] = half(memory[m][b][d])
__global__ __launch_bounds__(384) void memcvt_kernel(const float* __restrict__ src,
                                                     __half* __restrict__ dst) {
  int m = blockIdx.x, b = blockIdx.y, d = threadIdx.x;
  dst[((size_t)b * MM + m) * 384 + d] = __float2half(src[((size_t)m * 64 + b) * 384 + d]);
}

// k-pair interleaved fp16 weights
struct WcvtParams { const float* src[8]; unsigned* dst[8]; int tot[8]; int N[8]; };
__global__ __launch_bounds__(256) void wcvt_kernel(WcvtParams wp) {
  int job = blockIdx.y;
  const float* __restrict__ s = wp.src[job];
  unsigned* __restrict__ d = wp.dst[job];
  int n = wp.N[job], tot = wp.tot[job];
  for (int i = blockIdx.x * 256 + threadIdx.x; i < tot; i += gridDim.x * 256) {
    int k2 = i / n, j = i - k2 * n;
    d[i] = pack2(s[(size_t)(2 * k2) * n + j], s[(size_t)(2 * k2 + 1) * n + j]);
  }
}

// ---------------- LDS layout (bytes) ----------------
#define L_MPT    0         // mp_t half[192][256] = 98304
#define L_OVL    98304     // overlay: B2 redp 12*384f / A qp 4*192f / E gp2 4*384f + graw / G gip+ghp : 18432
#define L_SP3    116736    // 3*256 f = 3072
#define L_ES     119808    // 256 f = 1024
#define L_Q      120832    // 192 f = 768
#define L_XCF    121600    // 768 f = 3072
#define L_XC2    124672    // 384 u = 1536
#define L_G2     126208    // 384 u = 1536
#define L_GIS    127744    // 288 f = 1152
#define L_GHS    128896    // 288 f = 1152
#define L_HF     130048    // 192 f = 768
#define L_H2     130816    // 96 u = 384
#define L_VS     131200    // 192 f = 768
#define L_BIH    131968    // 288 f = 1152
#define L_BHH    133120    // 288 f = 1152
#define L_ZP     134272    // 16 f
#define L_MISC   134336    // 16 f
#define SCAN_LDS 134400
static_assert(SCAN_LDS <= 160 * 1024, "LDS overflow");

struct ScanParams {
  const float* input;        // [512][64][384] f32
  const unsigned* memt;      // [64][512][192] u (384 halfs)
  const unsigned* mptT[2];   // [64][192][256] u  ([b][a][m] halfs)
  const __half* xp[2];       // [512][64][192] half
  const unsigned* Wh2[2];    // [96][192] u
  const unsigned* Wg2[2];    // [384][768] u
  const unsigned* Wih2[2];   // [384][576] u
  const unsigned* Whh2[2];   // [96][576] u
  const float* v[2];
  const float* bih[2];
  const float* bhh[2];
  unsigned long long* ectx;  // [dirhalf][b][2 par][192] f32-pairs
  float* ez;                 // [dirhalf][b][2 par]
  unsigned* gmail;           // [dirhalf][b][2 par][192] packed half2
  unsigned* hmail;           // [dirhalf][b][2 par][48] packed half2
  unsigned* flags;           // 3 arrays x [dirhalf][b]
  float* out;                // [512][64][384]
};

__global__ __launch_bounds__(NTHR, 1) void scan_kernel(ScanParams p) {
  extern __shared__ char smem[];
  __half*   mp_s   = (__half*)(smem + L_MPT);
  float*    ovl    = (float*)(smem + L_OVL);
  float*    sp3    = (float*)(smem + L_SP3);
  float*    e_s    = (float*)(smem + L_ES);
  float*    q_s    = (float*)(smem + L_Q);
  float*    xc_f   = (float*)(smem + L_XCF);
  unsigned* xc2_s  = (unsigned*)(smem + L_XC2);
  unsigned* g2_s   = (unsigned*)(smem + L_G2);
  float*    gis    = (float*)(smem + L_GIS);
  float*    ghs    = (float*)(smem + L_GHS);
  float*    h_f    = (float*)(smem + L_HF);
  unsigned* h2_s   = (unsigned*)(smem + L_H2);
  float*    v_s    = (float*)(smem + L_VS);
  float*    bih_s  = (float*)(smem + L_BIH);
  float*    bhh_s  = (float*)(smem + L_BHH);
  float*    zp_s   = (float*)(smem + L_ZP);
  float*    misc_s = (float*)(smem + L_MISC);

  // same-XCD pairs: per XCD (dir fixed): 16 b's x 2 halves
  const int g = blockIdx.x;
  const int xcd = g & 7;
  const int slot = g >> 3;               // 0..31
  const int dir = xcd >> 2;
  const int b = (xcd & 3) * 16 + (slot >> 1);
  const int half = slot & 1;
  const int tid = threadIdx.x;
  const int lane = tid & 63;
  const int wv = tid >> 6;               // 0..11

  const unsigned* __restrict__ Wh2  = p.Wh2[dir];
  const unsigned* __restrict__ Wg2  = p.Wg2[dir];
  const unsigned* __restrict__ Wih2 = p.Wih2[dir];
  const unsigned* __restrict__ Whh2 = p.Whh2[dir];
  const __half* __restrict__ xp = p.xp[dir];
  const int m0 = half * 256;

  const int idx_my = (dir * 2 + half) * 64 + b;
  const int idx_p  = (dir * 2 + (half ^ 1)) * 64 + b;
  unsigned long long* myctx_u = p.ectx + (size_t)idx_my * 2 * 192;
  const unsigned long long* pctx_u = p.ectx + (size_t)idx_p * 2 * 192;
  float* myz0 = p.ez + (size_t)idx_my * 2;
  const float* pz0 = p.ez + (size_t)idx_p * 2;
  unsigned* gmail_my = p.gmail + (size_t)idx_my * 2 * 192;
  const unsigned* gmail_p = p.gmail + (size_t)idx_p * 2 * 192;
  unsigned* hmail_my = p.hmail + (size_t)idx_my * 2 * 48;
  const unsigned* hmail_p = p.hmail + (size_t)idx_p * 2 * 48;
  unsigned* fctx_my = p.flags + idx_my;        const unsigned* fctx_p = p.flags + idx_p;
  unsigned* fg_my   = p.flags + 256 + idx_my;  const unsigned* fg_p   = p.flags + 256 + idx_p;
  unsigned* fh_my   = p.flags + 512 + idx_my;  const unsigned* fh_p   = p.flags + 512 + idx_p;

  // ---- init: mp_t[a][m'] (my m-half), h=0, v, biases ----
  {
    const unsigned* mps = p.mptT[dir] + (size_t)b * 192 * 256 + half * 128;
    unsigned* mpd = (unsigned*)mp_s;
    for (int i = tid; i < 192 * 128; i += NTHR) {
      int a = i >> 7, mo = i & 127;
      mpd[i] = mps[(size_t)a * 256 + mo];
    }
    if (tid < 192) { h_f[tid] = 0.f; v_s[tid] = p.v[dir][tid]; }
    if (tid < 96) h2_s[tid] = 0u;
    if (tid < 288) {
      int c3 = tid / 96, jj = tid - c3 * 96;
      int col = c3 * 192 + 96 * half + jj;
      bih_s[tid] = p.bih[dir][col];
      bhh_s[tid] = p.bhh[dir][col];
    }
  }
  __syncthreads();

  #pragma unroll 1
  for (int t = 0; t < TT; ++t) {
    const int par = t & 1;
    // ---- A: q = xp + h @ Wh, (a x kq4) jobs ----
    {
      const int kq = tid / 192, a = tid - kq * 192;
      ovl[kq * 192 + a] = dotpipe<24, 192>(Wh2 + (size_t)(kq * 24) * 192 + a, h2_s + kq * 24);
    }
    __syncthreads();
    if (tid < 192)
      q_s[tid] = __half2float(xp[((size_t)t * 64 + b) * 192 + tid])
               + (ovl[tid] + ovl[192 + tid]) + (ovl[384 + tid] + ovl[576 + tid]);
    __syncthreads();

    // ---- B1: scores, lane-per-m (no shuffles); wave = (mblk, athird) ----
    {
      const int mblk = wv & 3, athird = wv >> 2;
      const int m = mblk * 64 + lane;
      float sacc = 0.f;
      const __half* mpa = mp_s + (athird * 64) * 256 + m;
      const float* qa = q_s + athird * 64;
      const float* va = v_s + athird * 64;
      #pragma unroll 4
      for (int i = 0; i < 64; ++i)
        sacc += va[i] * fast_tanh(__half2float(mpa[i * 256]) + qa[i]);
      sp3[athird * 256 + m] = sacc;
    }
    __syncthreads();
    if (tid < 256) {
      float s = sp3[tid] + sp3[256 + tid] + sp3[512 + tid];
      float e = __expf(s);
      e_s[tid] = e;
      float zr = e;
      #pragma unroll
      for (int off = 32; off > 0; off >>= 1) zr += __shfl_xor(zr, off, 64);
      if (lane == 0) zp_s[wv] = zr;
    }
    __syncthreads();

    // ---- B2: context accumulation (nt loads; 12 waves stride rows) ----
    {
      float c0 = 0, c1 = 0, c2 = 0, c3 = 0, c4 = 0, c5 = 0;
      const unsigned* mrowb = p.memt + ((size_t)b * MM + m0) * 192 + 3 * lane;
      #pragma unroll 2
      for (int i = wv; i < 256; i += 12) {
        const unsigned* mr = mrowb + (size_t)i * 192;
        unsigned u0 = __builtin_nontemporal_load(mr);
        unsigned u1 = __builtin_nontemporal_load(mr + 1);
        unsigned u2 = __builtin_nontemporal_load(mr + 2);
        float e = e_s[i];
        float2 f0 = h2f2(u0), f1 = h2f2(u1), f2 = h2f2(u2);
        c0 = fmaf(e, f0.x, c0); c1 = fmaf(e, f0.y, c1);
        c2 = fmaf(e, f1.x, c2); c3 = fmaf(e, f1.y, c3);
        c4 = fmaf(e, f2.x, c4); c5 = fmaf(e, f2.y, c5);
      }
      float2* rp2 = (float2*)(ovl + wv * 384);
      rp2[3 * lane]     = make_float2(c0, c1);
      rp2[3 * lane + 1] = make_float2(c2, c3);
      rp2[3 * lane + 2] = make_float2(c4, c5);
    }
    __syncthreads();

    // ---- C: combine 12 partials, send ctx+Z; load input row ----
    float zs = 0.f;
    if (tid < 192) {
      float cm0 = 0.f, cm1 = 0.f;
      #pragma unroll
      for (int k = 0; k < 12; ++k) {
        float2 v2r = ((const float2*)(ovl + k * 384))[tid];
        cm0 += v2r.x; cm1 += v2r.y;
      }
      misc_s[2] = 0.f;  // dummy keep
      // stash combined ctx (reuse sp3 as staging: 384 floats)
      sp3[2 * tid] = cm0; sp3[2 * tid + 1] = cm1;
      F2U u; u.f[0] = cm0; u.f[1] = cm1;
      astull(myctx_u + par * 192 + tid, u.u);
    }
    if (tid == 0) {
      zs = (zp_s[0] + zp_s[1]) + (zp_s[2] + zp_s[3]);
      ast(myz0 + par, zs);
    }
    if (tid < 384) xc_f[tid] = p.input[((size_t)(dir ? (TT - 1 - t) : t) * 64 + b) * 384 + tid];
    __syncthreads();   // drain atomic stores
    if (tid < 192) xc2_s[tid] = pack2(xc_f[2 * tid], xc_f[2 * tid + 1]);
    if (tid == 0) astu(fctx_my, (unsigned)(t + 1));
    __syncthreads();

    // ---- E1: gate input-half (kq x col) jobs; overlap ctx wait ----
    {
      const int kq = tid / 384, col = tid - kq * 384;
      ovl[kq * 384 + col] =
          dotpipe<96, 768>(Wg2 + (size_t)(kq * 96) * 768 + 384 * half + col, xc2_s + kq * 96);
    }
    if (tid == 0) {
      while (aldu(fctx_p) < (unsigned)(t + 1)) __builtin_amdgcn_s_sleep(1);
      float pz = ald(pz0 + par);
      misc_s[0] = __builtin_amdgcn_rcpf(zs + pz);
    }
    __syncthreads();

    // ---- D: ctx half of xc ----
    if (tid < 192) {
      F2U u; u.u = aldull(pctx_u + par * 192 + tid);
      float iz = misc_s[0];
      float x0 = (sp3[2 * tid] + u.f[0]) * iz;
      float x1 = (sp3[2 * tid + 1] + u.f[1]) * iz;
      xc_f[384 + 2 * tid] = x0;
      xc_f[384 + 2 * tid + 1] = x1;
      xc2_s[192 + tid] = pack2(x0, x1);
    }
    __syncthreads();

    // ---- E2: gate ctx-half ----
    {
      const int kq = tid / 384, col = tid - kq * 384;
      ovl[(2 + kq) * 384 + col] =
          dotpipe<96, 768>(Wg2 + (size_t)(192 + kq * 96) * 768 + 384 * half + col,
                           xc2_s + 192 + kq * 96);
    }
    __syncthreads();
    if (tid < 384) {
      float gsum = (ovl[tid] + ovl[384 + tid]) + (ovl[768 + tid] + ovl[1152 + tid]);
      ovl[1536 + tid] = fast_sigmoid(gsum) * xc_f[384 * half + tid];
    }
    __syncthreads();
    if (tid < 192) {
      unsigned pk = pack2(ovl[1536 + 2 * tid], ovl[1536 + 2 * tid + 1]);
      g2_s[192 * half + tid] = pk;
      astu(gmail_my + par * 192 + tid, pk);
    }
    __syncthreads();   // drain
    if (tid == 0) astu(fg_my, (unsigned)(t + 1));

    // ---- G1: gi own-k half (288 thr) + gh (192 thr); overlap g wait ----
    if (tid < 288) {
      const int c3 = tid / 96, jj = tid - c3 * 96;
      const int abscol = c3 * 192 + 96 * half + jj;
      ovl[tid] = dotpipe<192, 576>(Wih2 + (size_t)(192 * half) * 576 + abscol, g2_s + 192 * half);
    } else if (tid < 480) {
      #pragma unroll 1
      for (int r = 0; r < 3; ++r) {
        int j = (tid - 288) + 192 * r;
        int col = j % 288, kh2 = j / 288;
        int c3 = col / 96, jj = col - c3 * 96;
        int abscol = c3 * 192 + 96 * half + jj;
        ovl[512 + kh2 * 288 + col] =
            dotpipe<48, 576>(Whh2 + (size_t)(kh2 * 48) * 576 + abscol, h2_s + kh2 * 48);
      }
    }
    if (tid == 0) {
      while (aldu(fg_p) < (unsigned)(t + 1)) __builtin_amdgcn_s_sleep(1);
    }
    __syncthreads();
    // ---- F: fetch partner g ----
    if (tid < 192) g2_s[192 * (1 - half) + tid] = aldu(gmail_p + par * 192 + tid);
    __syncthreads();

    // ---- G2: gi partner-k half + combines ----
    if (tid < 288) {
      const int c3 = tid / 96, jj = tid - c3 * 96;
      const int abscol = c3 * 192 + 96 * half + jj;
      float go = dotpipe<192, 576>(Wih2 + (size_t)(192 * (1 - half)) * 576 + abscol,
                                   g2_s + 192 * (1 - half));
      gis[tid] = ovl[tid] + go + bih_s[tid];
    } else if (tid < 576) {
      int col = tid - 288;
      ghs[col] = ovl[512 + col] + ovl[512 + 288 + col] + bhh_s[col];
    }
    __syncthreads();

    // ---- H: GRU update (my 96 j's) ----
    if (tid < 96) {
      const int j = 96 * half + tid;
      float r = fast_sigmoid(gis[tid] + ghs[tid]);
      float z = fast_sigmoid(gis[96 + tid] + ghs[96 + tid]);
      float n = fast_tanh(gis[192 + tid] + r * ghs[192 + tid]);
      float hnew = (1.f - z) * n + z * h_f[j];
      h_f[j] = hnew;
      int trow = dir ? (TT - 1 - t) : t;
      p.out[((size_t)trow * 64 + b) * 384 + dir * 192 + j] = hnew;
    }
    __syncthreads();
    if (tid < 48) {
      unsigned pk = pack2(h_f[96 * half + 2 * tid], h_f[96 * half + 2 * tid + 1]);
      h2_s[48 * half + tid] = pk;
      astu(hmail_my + par * 48 + tid, pk);
    }
    __syncthreads();   // drain
    if (tid == 0) {
      astu(fh_my, (unsigned)(t + 1));
      while (aldu(fh_p) < (unsigned)(t + 1)) __builtin_amdgcn_s_sleep(1);
    }
    __syncthreads();
    if (tid < 48) h2_s[48 * (1 - half) + tid] = aldu(hmail_p + par * 48 + tid);
    __syncthreads();
  }
}

// ---------------- launcher ----------------
extern "C" void kernel_launch(void* const* d_in, const int* in_sizes, int n_in,
                              void* d_out, int out_size, void* d_ws, size_t ws_size,
                              hipStream_t stream) {
  (void)in_sizes; (void)n_in; (void)out_size;
  const float* memory = (const float*)d_in[0];
  const float* input  = (const float*)d_in[2];
  const float* Wm[2]  = {(const float*)d_in[3],  (const float*)d_in[12]};
  const float* Wx[2]  = {(const float*)d_in[4],  (const float*)d_in[13]};
  const float* Wh[2]  = {(const float*)d_in[5],  (const float*)d_in[14]};
  const float* v[2]   = {(const float*)d_in[6],  (const float*)d_in[15]};
  const float* Wg[2]  = {(const float*)d_in[7],  (const float*)d_in[16]};
  const float* Wih[2] = {(const float*)d_in[8],  (const float*)d_in[17]};
  const float* Whh[2] = {(const float*)d_in[9],  (const float*)d_in[18]};
  const float* bih[2] = {(const float*)d_in[10], (const float*)d_in[19]};
  const float* bhh[2] = {(const float*)d_in[11], (const float*)d_in[20]};

  char* ws = (char*)d_ws;
  const size_t OFF_FLAGS = 0;         // 4096
  const size_t OFF_EZ    = 4096;      // 2048
  const size_t OFF_GMAIL = 6144;      // 786432
  const size_t OFF_HMAIL = 792576;    // 196608
  const size_t OFF_ECTX  = 989184;    // 786432
  const size_t OFF_MPT0  = 1775616;
  const size_t OFF_MPT1  = OFF_MPT0 + 12582912;
  const size_t OFF_XP0   = OFF_MPT1 + 12582912;
  const size_t OFF_XP1   = OFF_XP0 + 12582912;
  const size_t OFF_MT    = OFF_XP1 + 12582912;
  const size_t OFF_WG0   = OFF_MT + 25165824;
  const size_t OFF_WG1   = OFF_WG0 + 1179648;
  const size_t OFF_WIH0  = OFF_WG1 + 1179648;
  const size_t OFF_WIH1  = OFF_WIH0 + 884736;
  const size_t OFF_WHH0  = OFF_WIH1 + 884736;
  const size_t OFF_WHH1  = OFF_WHH0 + 221184;
  const size_t OFF_WH0   = OFF_WHH1 + 221184;
  const size_t OFF_WH1   = OFF_WH0 + 73728;
  const size_t NEEDED    = OFF_WH1 + 73728;   // ~82 MB
  if (ws_size < NEEDED) return;

  unsigned* flags = (unsigned*)(ws + OFF_FLAGS);
  float* ez    = (float*)(ws + OFF_EZ);
  unsigned* gmail = (unsigned*)(ws + OFF_GMAIL);
  unsigned* hmail = (unsigned*)(ws + OFF_HMAIL);
  unsigned long long* ectx = (unsigned long long*)(ws + OFF_ECTX);
  __half* mpt0 = (__half*)(ws + OFF_MPT0);
  __half* mpt1 = (__half*)(ws + OFF_MPT1);
  __half* xp0  = (__half*)(ws + OFF_XP0);
  __half* xp1  = (__half*)(ws + OFF_XP1);
  __half* memt = (__half*)(ws + OFF_MT);
  unsigned* wg2[2]  = {(unsigned*)(ws + OFF_WG0),  (unsigned*)(ws + OFF_WG1)};
  unsigned* wih2[2] = {(unsigned*)(ws + OFF_WIH0), (unsigned*)(ws + OFF_WIH1)};
  unsigned* whh2[2] = {(unsigned*)(ws + OFF_WHH0), (unsigned*)(ws + OFF_WHH1)};
  unsigned* wh2[2]  = {(unsigned*)(ws + OFF_WH0),  (unsigned*)(ws + OFF_WH1)};

  hipFuncSetAttribute(reinterpret_cast<const void*>(scan_kernel),
                      hipFuncAttributeMaxDynamicSharedMemorySize, SCAN_LDS);

  hipMemsetAsync(ws + OFF_FLAGS, 0, 4096, stream);   // flags only

  ProjParams pp;
  pp.X[0] = memory; pp.W[0] = Wm[0]; pp.C[0] = mpt0; pp.rev[0] = 0; pp.transp[0] = 2;
  pp.X[1] = memory; pp.W[1] = Wm[1]; pp.C[1] = mpt1; pp.rev[1] = 0; pp.transp[1] = 2;
  pp.X[2] = input;  pp.W[2] = Wx[0]; pp.C[2] = xp0;  pp.rev[2] = 0; pp.transp[2] = 0;
  pp.X[3] = input;  pp.W[3] = Wx[1]; pp.C[3] = xp1;  pp.rev[3] = 1; pp.transp[3] = 0;
  proj_kernel<<<dim3(1024, 4), dim3(192), 0, stream>>>(pp);
  memcvt_kernel<<<dim3(MM, 64), dim3(384), 0, stream>>>(memory, memt);

  WcvtParams wp;
  for (int d = 0; d < 2; ++d) {
    wp.src[d]     = Wg[d];  wp.dst[d]     = wg2[d];  wp.tot[d]     = 384 * 768; wp.N[d]     = 768;
    wp.src[2 + d] = Wih[d]; wp.dst[2 + d] = wih2[d]; wp.tot[2 + d] = 384 * 576; wp.N[2 + d] = 576;
    wp.src[4 + d] = Whh[d]; wp.dst[4 + d] = whh2[d]; wp.tot[4 + d] = 96 * 576;  wp.N[4 + d] = 576;
    wp.src[6 + d] = Wh[d];  wp.dst[6 + d] = wh2[d];  wp.tot[6 + d] = 96 * 192;  wp.N[6 + d] = 192;
  }
  wcvt_kernel<<<dim3(288, 8), dim3(256), 0, stream>>>(wp);

  ScanParams sp;
  sp.input = input;
  sp.memt = (const unsigned*)memt;
  sp.mptT[0] = (const unsigned*)mpt0; sp.mptT[1] = (const unsigned*)mpt1;
  sp.xp[0] = xp0; sp.xp[1] = xp1;
  for (int d = 0; d < 2; ++d) {
    sp.Wh2[d] = wh2[d]; sp.Wg2[d] = wg2[d]; sp.Wih2[d] = wih2[d]; sp.Whh2[d] = whh2[d];
    sp.v[d] = v[d]; sp.bih[d] = bih[d]; sp.bhh[d] = bhh[d];
  }
  sp.ectx = ectx; sp.ez = ez; sp.gmail = gmail; sp.hmail = hmail; sp.flags = flags;
  sp.out = (float*)d_out;
  scan_kernel<<<dim3(NWG), dim3(NTHR), SCAN_LDS, stream>>>(sp);
}

// Round 7
// 22435.153 us; speedup vs baseline: 1.2053x; 1.2053x over previous
//
#include <hip/hip_runtime.h>
#include <hip/hip_fp16.h>

#define TT 512
#define MM 512
#define NWG 256

// ---------------- fast math ----------------
__device__ __forceinline__ float fast_sigmoid(float x) {
  float e = __expf(-x);
  return __builtin_amdgcn_rcpf(1.f + e);
}
__device__ __forceinline__ float fast_tanh(float x) {
  float e = __expf(2.f * x);
  return 1.f - 2.f * __builtin_amdgcn_rcpf(e + 1.f);
}
__device__ __forceinline__ float2 h2f2(unsigned u) {
  __half2 h = *reinterpret_cast<__half2*>(&u);
  return __half22float2(h);
}
__device__ __forceinline__ unsigned pack2(float x, float y) {
  __half2 h = __floats2half2_rn(x, y);
  return *reinterpret_cast<unsigned*>(&h);
}

typedef _Float16 hf2_t __attribute__((ext_vector_type(2)));
__device__ __forceinline__ float fdot2f(unsigned a, unsigned b, float c) {
#if __has_builtin(__builtin_amdgcn_fdot2)
  union U { unsigned u; hf2_t h; };
  U ua, ub; ua.u = a; ub.u = b;
  return __builtin_amdgcn_fdot2(ua.h, ub.h, c, false);
#else
  float2 fa = h2f2(a), fb = h2f2(b);
  return fmaf(fa.x, fb.x, fmaf(fa.y, fb.y, c));
#endif
}

// 24-deep software-pipelined dot: w strided by S (global), x2 in LDS. K%24==0.
template<int K, int S>
__device__ __forceinline__ float dotpipe(const unsigned* __restrict__ w,
                                         const unsigned* __restrict__ x2) {
  unsigned A[12], B[12];
  float acc[4] = {0.f, 0.f, 0.f, 0.f};
  #pragma unroll
  for (int i = 0; i < 12; ++i) A[i] = w[(size_t)i * S];
  #pragma unroll 1
  for (int k = 0; k < K; k += 24) {
    #pragma unroll
    for (int i = 0; i < 12; ++i) B[i] = w[(size_t)(k + 12 + i) * S];
    #pragma unroll
    for (int i = 0; i < 12; ++i) acc[i & 3] = fdot2f(A[i], x2[k + i], acc[i & 3]);
    if (k + 24 < K) {
      #pragma unroll
      for (int i = 0; i < 12; ++i) A[i] = w[(size_t)(k + 24 + i) * S];
    }
    #pragma unroll
    for (int i = 0; i < 12; ++i) acc[i & 3] = fdot2f(B[i], x2[k + 12 + i], acc[i & 3]);
  }
  return (acc[0] + acc[1]) + (acc[2] + acc[3]);
}

// ---------------- agent-scope atomics ----------------
__device__ __forceinline__ void ast(float* p, float v) {
  __hip_atomic_store(p, v, __ATOMIC_RELAXED, __HIP_MEMORY_SCOPE_AGENT);
}
__device__ __forceinline__ float ald(const float* p) {
  return __hip_atomic_load(p, __ATOMIC_RELAXED, __HIP_MEMORY_SCOPE_AGENT);
}
__device__ __forceinline__ void astu(unsigned* p, unsigned v) {
  __hip_atomic_store(p, v, __ATOMIC_RELAXED, __HIP_MEMORY_SCOPE_AGENT);
}
__device__ __forceinline__ unsigned aldu(const unsigned* p) {
  return __hip_atomic_load(p, __ATOMIC_RELAXED, __HIP_MEMORY_SCOPE_AGENT);
}
__device__ __forceinline__ void astull(unsigned long long* p, unsigned long long v) {
  __hip_atomic_store(p, v, __ATOMIC_RELAXED, __HIP_MEMORY_SCOPE_AGENT);
}
__device__ __forceinline__ unsigned long long aldull(const unsigned long long* p) {
  return __hip_atomic_load(p, __ATOMIC_RELAXED, __HIP_MEMORY_SCOPE_AGENT);
}
union F2U { unsigned long long u; float f[2]; };

// ---------------- precompute: proj (fp16 out, optional transpose / reversal) ----------------
struct ProjParams {
  const float* X[4]; const float* W[4]; __half* C[4]; int rev[4]; int transp[4];
};

__global__ __launch_bounds__(192) void proj_kernel(ProjParams pp) {
  __shared__ float xs[32 * 384];
  const int job = blockIdx.y;
  const float* __restrict__ X = pp.X[job];
  const float* __restrict__ W = pp.W[job];
  __half* __restrict__ C = pp.C[job];
  const int rev = pp.rev[job];
  const int transp = pp.transp[job];
  const int r0 = blockIdx.x * 32;
  const int tid = threadIdx.x;

  for (int idx = tid; idx < 32 * 384; idx += 192) {
    int r = idx / 384, k = idx - r * 384;
    int row = r0 + r;
    int srow = row;
    if (rev) { int t = row >> 6, b2 = row & 63; srow = ((TT - 1 - t) << 6) | b2; }
    xs[idx] = X[(size_t)srow * 384 + k];
  }
  __syncthreads();

  float acc[32];
  #pragma unroll
  for (int r = 0; r < 32; ++r) acc[r] = 0.f;
  for (int k = 0; k < 384; ++k) {
    float w = W[k * 192 + tid];
    #pragma unroll
    for (int r = 0; r < 32; ++r) acc[r] = fmaf(xs[r * 384 + k], w, acc[r]);
  }
  #pragma unroll
  for (int r = 0; r < 32; ++r) {
    int row = r0 + r;
    size_t di = transp ? (((size_t)(row & 63) * MM + (row >> 6)) * 192 + tid)
                       : ((size_t)row * 192 + tid);
    C[di] = __float2half(acc[r]);
  }
}

// memt[b][m][d] = half(memory[m][b][d])
__global__ __launch_bounds__(384) void memcvt_kernel(const float* __restrict__ src,
                                                     __half* __restrict__ dst) {
  int m = blockIdx.x, b = blockIdx.y, d = threadIdx.x;
  dst[((size_t)b * MM + m) * 384 + d] = __float2half(src[((size_t)m * 64 + b) * 384 + d]);
}

// k-pair interleaved fp16 weights: dst[k2*N+j] = pack(src[2k2][j], src[2k2+1][j])
struct WcvtParams { const float* src[8]; unsigned* dst[8]; int tot[8]; int N[8]; };
__global__ __launch_bounds__(256) void wcvt_kernel(WcvtParams wp) {
  int job = blockIdx.y;
  const float* __restrict__ s = wp.src[job];
  unsigned* __restrict__ d = wp.dst[job];
  int n = wp.N[job], tot = wp.tot[job];
  for (int i = blockIdx.x * 256 + threadIdx.x; i < tot; i += gridDim.x * 256) {
    int k2 = i / n, j = i - k2 * n;
    d[i] = pack2(s[(size_t)(2 * k2) * n + j], s[(size_t)(2 * k2 + 1) * n + j]);
  }
}

// ---------------- LDS layout (bytes) ----------------
#define L_MP     0         // 256*192 halfs = 98304
#define L_REDP   98304     // 8*384 f = 12288
#define L_SH384  110592    // q-parts / ctx-mine / raw g overlay: 384 f
#define L_Q      112128    // 192 f
#define L_XCF    112896    // 768 f
#define L_XC2    115968    // 384 u
#define L_G2     117504    // 384 u
#define L_GIS    119040    // 288 f
#define L_GHS    120192    // 288 f
#define L_HF     121344    // 192 f
#define L_H2     122112    // 96 u
#define L_VS     122496    // 192 f
#define L_BIH    123264    // 288 f
#define L_BHH    124416    // 288 f
#define L_ZP     125568    // 8 f
#define L_MISC   125600    // 8 f
#define L_ES     125632    // 256 f = 1024
#define SCAN_LDS 126656
static_assert(SCAN_LDS <= 160 * 1024, "LDS overflow");

struct ScanParams {
  const float* input;        // [512][64][384] f32
  const unsigned* memt;      // [64][512][192] u (384 halfs)
  const unsigned* mpt[2];    // [64][512][96] u (192 halfs)
  const __half* xp[2];       // [512][64][192] half
  const unsigned* Wh2[2];    // [96][192] u
  const unsigned* Wg2[2];    // [384][768] u
  const unsigned* Wih2[2];   // [384][576] u
  const unsigned* Whh2[2];   // [96][576] u
  const float* v[2];
  const float* bih[2];
  const float* bhh[2];
  unsigned long long* ectx;  // [dirhalf][b][2 par][192] f32-pairs
  float* ez;                 // [dirhalf][b][2 par]
  unsigned* gmail;           // [dirhalf][b][2 par][192] packed half2
  unsigned* hmail;           // [dirhalf][b][2 par][48] packed half2
  unsigned* flags;           // 3 arrays x [dirhalf][b]
  float* out;                // [512][64][384]
};

__global__ __launch_bounds__(512, 1) void scan_kernel(ScanParams p) {
  extern __shared__ char smem[];
  __half*   mp_s   = (__half*)(smem + L_MP);
  float*    redp   = (float*)(smem + L_REDP);
  float*    sh384  = (float*)(smem + L_SH384);
  float*    q_s    = (float*)(smem + L_Q);
  float*    xc_f   = (float*)(smem + L_XCF);
  unsigned* xc2_s  = (unsigned*)(smem + L_XC2);
  unsigned* g2_s   = (unsigned*)(smem + L_G2);
  float*    gis    = (float*)(smem + L_GIS);
  float*    ghs    = (float*)(smem + L_GHS);
  float*    h_f    = (float*)(smem + L_HF);
  unsigned* h2_s   = (unsigned*)(smem + L_H2);
  float*    v_s    = (float*)(smem + L_VS);
  float*    bih_s  = (float*)(smem + L_BIH);
  float*    bhh_s  = (float*)(smem + L_BHH);
  float*    zp_s   = (float*)(smem + L_ZP);
  float*    misc_s = (float*)(smem + L_MISC);
  float*    e_s    = (float*)(smem + L_ES);

  // XCD-grouped mapping: xcd 0-3 -> dir0, 4-7 -> dir1
  const int g = blockIdx.x;
  const int xcd = g & 7;
  const int slot = g >> 3;
  const int dir = xcd >> 2;
  const int idx = (xcd & 3) * 32 + slot;   // 0..127
  const int b = idx & 63;
  const int half = idx >> 6;
  const int tid = threadIdx.x;
  const int lane = tid & 63;
  const int wv = tid >> 6;

  const unsigned* __restrict__ Wh2  = p.Wh2[dir];
  const unsigned* __restrict__ Wg2  = p.Wg2[dir];
  const unsigned* __restrict__ Wih2 = p.Wih2[dir];
  const unsigned* __restrict__ Whh2 = p.Whh2[dir];
  const __half* __restrict__ xp = p.xp[dir];
  const int m0 = half * 256;

  const int idx_my = (dir * 2 + half) * 64 + b;
  const int idx_p  = (dir * 2 + (half ^ 1)) * 64 + b;
  unsigned long long* myctx_u = p.ectx + (size_t)idx_my * 2 * 192;
  const unsigned long long* pctx_u = p.ectx + (size_t)idx_p * 2 * 192;
  float* myz0 = p.ez + (size_t)idx_my * 2;
  const float* pz0 = p.ez + (size_t)idx_p * 2;
  unsigned* gmail_my = p.gmail + (size_t)idx_my * 2 * 192;
  const unsigned* gmail_p = p.gmail + (size_t)idx_p * 2 * 192;
  unsigned* hmail_my = p.hmail + (size_t)idx_my * 2 * 48;
  const unsigned* hmail_p = p.hmail + (size_t)idx_p * 2 * 48;
  unsigned* fctx_my = p.flags + idx_my;        const unsigned* fctx_p = p.flags + idx_p;
  unsigned* fg_my   = p.flags + 256 + idx_my;  const unsigned* fg_p   = p.flags + 256 + idx_p;
  unsigned* fh_my   = p.flags + 512 + idx_my;  const unsigned* fh_p   = p.flags + 512 + idx_p;

  // ---- init ----
  {
    const unsigned* mpu = p.mpt[dir] + ((size_t)b * MM + m0) * 96;
    unsigned* mpd = (unsigned*)mp_s;
    for (int i = tid; i < 256 * 96; i += 512) mpd[i] = mpu[i];
    if (tid < 192) { h_f[tid] = 0.f; v_s[tid] = p.v[dir][tid]; }
    if (tid < 96) h2_s[tid] = 0u;
    if (tid < 288) {
      int c3 = tid / 96, jj = tid - c3 * 96;
      int col = c3 * 192 + 96 * half + jj;
      bih_s[tid] = p.bih[dir][col];
      bhh_s[tid] = p.bhh[dir][col];
    }
  }
  __syncthreads();
  const float v0 = v_s[lane], v1 = v_s[lane + 64], v2 = v_s[lane + 128];

  #pragma unroll 1
  for (int t = 0; t < TT; ++t) {
    const int par = t & 1;
    // ---- A: q = xp[t,b,:] + h @ Wh ----
    if (tid < 384) {
      const int kh = (tid >= 192);
      const int a = tid - 192 * kh;
      sh384[tid] = dotpipe<48, 192>(Wh2 + (size_t)kh * 48 * 192 + a, h2_s + kh * 48);
    }
    __syncthreads();
    if (tid < 192)
      q_s[tid] = __half2float(xp[((size_t)t * 64 + b) * 192 + tid]) + sh384[tid] + sh384[192 + tid];
    __syncthreads();

    // ---- B1: scores for my 256 rows -> e_s, per-wave Z ----
    {
      const float q0 = q_s[lane], q1 = q_s[lane + 64], q2 = q_s[lane + 128];
      float zacc = 0.f;
      const __half* mph = mp_s + (wv * 32) * 192;
      #pragma unroll 4
      for (int i = 0; i < 32; ++i) {
        const __half* r = mph + i * 192;
        float s = v0 * fast_tanh(__half2float(r[lane]) + q0)
                + v1 * fast_tanh(__half2float(r[lane + 64]) + q1)
                + v2 * fast_tanh(__half2float(r[lane + 128]) + q2);
        #pragma unroll
        for (int off = 32; off > 0; off >>= 1) s += __shfl_xor(s, off, 64);
        float e = __expf(s);
        zacc += e;
        if (lane == 0) e_s[wv * 32 + i] = e;
      }
      if (lane == 0) zp_s[wv] = zacc;
    }
    __syncthreads();
    // ---- B2: context, uint4 loads (16B/slot), lanes 0-47, unroll 8 ----
    {
      float ca[8] = {0, 0, 0, 0, 0, 0, 0, 0};
      if (lane < 48) {
        const uint4* mrow4 = (const uint4*)(p.memt + ((size_t)b * MM + m0 + wv * 32) * 192) + lane;
        const float* es = e_s + wv * 32;
        #pragma unroll 8
        for (int i = 0; i < 32; ++i) {
          uint4 mv = mrow4[(size_t)i * 48];
          float e = es[i];
          float2 f0 = h2f2(mv.x), f1 = h2f2(mv.y), f2 = h2f2(mv.z), f3 = h2f2(mv.w);
          ca[0] = fmaf(e, f0.x, ca[0]); ca[1] = fmaf(e, f0.y, ca[1]);
          ca[2] = fmaf(e, f1.x, ca[2]); ca[3] = fmaf(e, f1.y, ca[3]);
          ca[4] = fmaf(e, f2.x, ca[4]); ca[5] = fmaf(e, f2.y, ca[5]);
          ca[6] = fmaf(e, f3.x, ca[6]); ca[7] = fmaf(e, f3.y, ca[7]);
        }
        float2* rp2 = (float2*)(redp + wv * 384 + 8 * lane);
        rp2[0] = make_float2(ca[0], ca[1]);
        rp2[1] = make_float2(ca[2], ca[3]);
        rp2[2] = make_float2(ca[4], ca[5]);
        rp2[3] = make_float2(ca[6], ca[7]);
      }
    }
    __syncthreads();

    // ---- C: combine partials, send; load input row ----
    float zs = 0.f;
    if (tid < 192) {
      float cm0 = 0.f, cm1 = 0.f;
      const float2* rp2 = (const float2*)redp;
      #pragma unroll
      for (int k = 0; k < 8; ++k) {
        float2 v2r = rp2[k * 192 + tid];
        cm0 += v2r.x; cm1 += v2r.y;
      }
      sh384[2 * tid] = cm0; sh384[2 * tid + 1] = cm1;
      F2U u; u.f[0] = cm0; u.f[1] = cm1;
      astull(myctx_u + par * 192 + tid, u.u);
    }
    if (tid == 0) {
      #pragma unroll
      for (int k = 0; k < 8; ++k) zs += zp_s[k];
      ast(myz0 + par, zs);
    }
    const int xt = dir ? (TT - 1 - t) : t;
    if (tid < 384) xc_f[tid] = p.input[((size_t)xt * 64 + b) * 384 + tid];
    __syncthreads();   // drains atomic stores; xc_f ready
    if (tid < 192) xc2_s[tid] = pack2(xc_f[2 * tid], xc_f[2 * tid + 1]);
    if (tid == 0) astu(fctx_my, (unsigned)(t + 1));
    __syncthreads();   // xc2 input half visible

    // ---- E1: gate partial over input half (overlaps partner ctx wait) ----
    float eacc = 0.f;
    if (tid < 384) {
      const int col = 384 * half + tid;
      eacc = dotpipe<192, 768>(Wg2 + col, xc2_s);
    }
    // ---- ghs on idle waves 6-7 (needs only h2_s, stable this step) ----
    if (tid >= 384) {
      for (int jj = tid - 384; jj < 288; jj += 128) {
        const int c3 = jj / 96;
        const int col = c3 * 192 + 96 * half + (jj - c3 * 96);
        ghs[jj] = dotpipe<96, 576>(Whh2 + col, h2_s) + bhh_s[jj];
      }
    }
    if (tid == 0) {
      while (aldu(fctx_p) < (unsigned)(t + 1)) __builtin_amdgcn_s_sleep(1);
      float pz = ald(pz0 + par);
      misc_s[0] = __builtin_amdgcn_rcpf(zs + pz);
    }
    __syncthreads();

    // ---- D: ctx half of xc ----
    if (tid < 192) {
      F2U u; u.u = aldull(pctx_u + par * 192 + tid);
      float iz = misc_s[0];
      float x0 = (sh384[2 * tid] + u.f[0]) * iz;
      float x1 = (sh384[2 * tid + 1] + u.f[1]) * iz;
      xc_f[384 + 2 * tid] = x0;
      xc_f[384 + 2 * tid + 1] = x1;
      xc2_s[192 + tid] = pack2(x0, x1);
    }
    __syncthreads();

    // ---- E2: finish gate ----
    if (tid < 384) {
      const int col = 384 * half + tid;
      eacc += dotpipe<192, 768>(Wg2 + (size_t)192 * 768 + col, xc2_s + 192);
      sh384[tid] = fast_sigmoid(eacc) * xc_f[col];
    }
    __syncthreads();
    if (tid < 192) {
      unsigned pk = pack2(sh384[2 * tid], sh384[2 * tid + 1]);
      g2_s[192 * half + tid] = pk;
      astu(gmail_my + par * 192 + tid, pk);
    }
    __syncthreads();   // drain mailbox stores
    if (tid == 0) astu(fg_my, (unsigned)(t + 1));

    // ---- G1: gi partial over my g half (overlaps partner gate) ----
    float gacc = 0.f;
    if (tid < 288) {
      const int c3 = tid / 96, jj = tid - c3 * 96;
      const int col = c3 * 192 + 96 * half + jj;
      gacc = dotpipe<192, 576>(Wih2 + (size_t)(192 * half) * 576 + col, g2_s + 192 * half);
    }
    if (tid == 0) {
      while (aldu(fg_p) < (unsigned)(t + 1)) __builtin_amdgcn_s_sleep(1);
    }
    __syncthreads();
    // ---- F: fetch partner g half ----
    if (tid < 192) g2_s[192 * (1 - half) + tid] = aldu(gmail_p + par * 192 + tid);
    __syncthreads();

    // ---- G2: finish gi ----
    if (tid < 288) {
      const int c3 = tid / 96, jj = tid - c3 * 96;
      const int col = c3 * 192 + 96 * half + jj;
      gis[tid] = gacc + bih_s[tid]
               + dotpipe<192, 576>(Wih2 + (size_t)(192 * (1 - half)) * 576 + col,
                                   g2_s + 192 * (1 - half));
    }
    __syncthreads();

    // ---- H: GRU update (my 96 j's) ----
    if (tid < 96) {
      const int j = 96 * half + tid;
      float r = fast_sigmoid(gis[tid] + ghs[tid]);
      float z = fast_sigmoid(gis[96 + tid] + ghs[96 + tid]);
      float n = fast_tanh(gis[192 + tid] + r * ghs[192 + tid]);
      float hnew = (1.f - z) * n + z * h_f[j];
      h_f[j] = hnew;
      int trow = dir ? (TT - 1 - t) : t;
      p.out[((size_t)trow * 64 + b) * 384 + dir * 192 + j] = hnew;
    }
    __syncthreads();
    if (tid < 48) {
      unsigned pk = pack2(h_f[96 * half + 2 * tid], h_f[96 * half + 2 * tid + 1]);
      h2_s[48 * half + tid] = pk;
      astu(hmail_my + par * 48 + tid, pk);
    }
    __syncthreads();   // drain
    if (tid == 0) {
      astu(fh_my, (unsigned)(t + 1));
      while (aldu(fh_p) < (unsigned)(t + 1)) __builtin_amdgcn_s_sleep(1);
    }
    __syncthreads();
    if (tid < 48) h2_s[48 * (1 - half) + tid] = aldu(hmail_p + par * 48 + tid);
    __syncthreads();
  }
}

// ---------------- launcher ----------------
extern "C" void kernel_launch(void* const* d_in, const int* in_sizes, int n_in,
                              void* d_out, int out_size, void* d_ws, size_t ws_size,
                              hipStream_t stream) {
  (void)in_sizes; (void)n_in; (void)out_size;
  const float* memory = (const float*)d_in[0];
  const float* input  = (const float*)d_in[2];
  const float* Wm[2]  = {(const float*)d_in[3],  (const float*)d_in[12]};
  const float* Wx[2]  = {(const float*)d_in[4],  (const float*)d_in[13]};
  const float* Wh[2]  = {(const float*)d_in[5],  (const float*)d_in[14]};
  const float* v[2]   = {(const float*)d_in[6],  (const float*)d_in[15]};
  const float* Wg[2]  = {(const float*)d_in[7],  (const float*)d_in[16]};
  const float* Wih[2] = {(const float*)d_in[8],  (const float*)d_in[17]};
  const float* Whh[2] = {(const float*)d_in[9],  (const float*)d_in[18]};
  const float* bih[2] = {(const float*)d_in[10], (const float*)d_in[19]};
  const float* bhh[2] = {(const float*)d_in[11], (const float*)d_in[20]};

  char* ws = (char*)d_ws;
  const size_t OFF_FLAGS = 0;         // 4096 (3 flag arrays x 256 u32)
  const size_t OFF_EZ    = 4096;      // 2048
  const size_t OFF_GMAIL = 6144;      // 786432
  const size_t OFF_HMAIL = 792576;    // 196608
  const size_t OFF_ECTX  = 989184;    // 786432
  const size_t OFF_MPT0  = 1775616;
  const size_t OFF_MPT1  = OFF_MPT0 + 12582912;
  const size_t OFF_XP0   = OFF_MPT1 + 12582912;
  const size_t OFF_XP1   = OFF_XP0 + 12582912;
  const size_t OFF_MT    = OFF_XP1 + 12582912;
  const size_t OFF_WG0   = OFF_MT + 25165824;
  const size_t OFF_WG1   = OFF_WG0 + 1179648;
  const size_t OFF_WIH0  = OFF_WG1 + 1179648;
  const size_t OFF_WIH1  = OFF_WIH0 + 884736;
  const size_t OFF_WHH0  = OFF_WIH1 + 884736;
  const size_t OFF_WHH1  = OFF_WHH0 + 221184;
  const size_t OFF_WH0   = OFF_WHH1 + 221184;
  const size_t OFF_WH1   = OFF_WH0 + 73728;
  const size_t NEEDED    = OFF_WH1 + 73728;   // ~82 MB
  if (ws_size < NEEDED) return;

  unsigned* flags = (unsigned*)(ws + OFF_FLAGS);
  float* ez    = (float*)(ws + OFF_EZ);
  unsigned* gmail = (unsigned*)(ws + OFF_GMAIL);
  unsigned* hmail = (unsigned*)(ws + OFF_HMAIL);
  unsigned long long* ectx = (unsigned long long*)(ws + OFF_ECTX);
  __half* mpt0 = (__half*)(ws + OFF_MPT0);
  __half* mpt1 = (__half*)(ws + OFF_MPT1);
  __half* xp0  = (__half*)(ws + OFF_XP0);
  __half* xp1  = (__half*)(ws + OFF_XP1);
  __half* memt = (__half*)(ws + OFF_MT);
  unsigned* wg2[2]  = {(unsigned*)(ws + OFF_WG0),  (unsigned*)(ws + OFF_WG1)};
  unsigned* wih2[2] = {(unsigned*)(ws + OFF_WIH0), (unsigned*)(ws + OFF_WIH1)};
  unsigned* whh2[2] = {(unsigned*)(ws + OFF_WHH0), (unsigned*)(ws + OFF_WHH1)};
  unsigned* wh2[2]  = {(unsigned*)(ws + OFF_WH0),  (unsigned*)(ws + OFF_WH1)};

  hipFuncSetAttribute(reinterpret_cast<const void*>(scan_kernel),
                      hipFuncAttributeMaxDynamicSharedMemorySize, SCAN_LDS);

  hipMemsetAsync(ws + OFF_FLAGS, 0, 4096, stream);   // flags only

  ProjParams pp;
  pp.X[0] = memory; pp.W[0] = Wm[0]; pp.C[0] = mpt0; pp.rev[0] = 0; pp.transp[0] = 1;
  pp.X[1] = memory; pp.W[1] = Wm[1]; pp.C[1] = mpt1; pp.rev[1] = 0; pp.transp[1] = 1;
  pp.X[2] = input;  pp.W[2] = Wx[0]; pp.C[2] = xp0;  pp.rev[2] = 0; pp.transp[2] = 0;
  pp.X[3] = input;  pp.W[3] = Wx[1]; pp.C[3] = xp1;  pp.rev[3] = 1; pp.transp[3] = 0;
  proj_kernel<<<dim3(1024, 4), dim3(192), 0, stream>>>(pp);
  memcvt_kernel<<<dim3(MM, 64), dim3(384), 0, stream>>>(memory, memt);

  WcvtParams wp;
  for (int d = 0; d < 2; ++d) {
    wp.src[d]     = Wg[d];  wp.dst[d]     = wg2[d];  wp.tot[d]     = 384 * 768; wp.N[d]     = 768;
    wp.src[2 + d] = Wih[d]; wp.dst[2 + d] = wih2[d]; wp.tot[2 + d] = 384 * 576; wp.N[2 + d] = 576;
    wp.src[4 + d] = Whh[d]; wp.dst[4 + d] = whh2[d]; wp.tot[4 + d] = 96 * 576;  wp.N[4 + d] = 576;
    wp.src[6 + d] = Wh[d];  wp.dst[6 + d] = wh2[d];  wp.tot[6 + d] = 96 * 192;  wp.N[6 + d] = 192;
  }
  wcvt_kernel<<<dim3(288, 8), dim3(256), 0, stream>>>(wp);

  ScanParams sp;
  sp.input = input;
  sp.memt = (const unsigned*)memt;
  sp.mpt[0] = (const unsigned*)mpt0; sp.mpt[1] = (const unsigned*)mpt1;
  sp.xp[0] = xp0; sp.xp[1] = xp1;
  for (int d = 0; d < 2; ++d) {
    sp.Wh2[d] = wh2[d]; sp.Wg2[d] = wg2[d]; sp.Wih2[d] = wih2[d]; sp.Whh2[d] = whh2[d];
    sp.v[d] = v[d]; sp.bih[d] = bih[d]; sp.bhh[d] = bhh[d];
  }
  sp.ectx = ectx; sp.ez = ez; sp.gmail = gmail; sp.hmail = hmail; sp.flags = flags;
  sp.out = (float*)d_out;
  scan_kernel<<<dim3(NWG), dim3(512), SCAN_LDS, stream>>>(sp);
}

// Round 9
// 22291.554 us; speedup vs baseline: 1.2131x; 1.0064x over previous
//
#include <hip/hip_runtime.h>
#include <hip/hip_fp16.h>

#define TT 512
#define MM 512
#define NWG 256

// ---------------- fast math ----------------
__device__ __forceinline__ float fast_sigmoid(float x) {
  float e = __expf(-x);
  return __builtin_amdgcn_rcpf(1.f + e);
}
__device__ __forceinline__ float fast_tanh(float x) {
  float e = __expf(2.f * x);
  return 1.f - 2.f * __builtin_amdgcn_rcpf(e + 1.f);
}
__device__ __forceinline__ float2 h2f2(unsigned u) {
  __half2 h = *reinterpret_cast<__half2*>(&u);
  return __half22float2(h);
}
__device__ __forceinline__ unsigned pack2(float x, float y) {
  __half2 h = __floats2half2_rn(x, y);
  return *reinterpret_cast<unsigned*>(&h);
}

typedef _Float16 hf2_t __attribute__((ext_vector_type(2)));
__device__ __forceinline__ float fdot2f(unsigned a, unsigned b, float c) {
#if __has_builtin(__builtin_amdgcn_fdot2)
  union U { unsigned u; hf2_t h; };
  U ua, ub; ua.u = a; ub.u = b;
  return __builtin_amdgcn_fdot2(ua.h, ub.h, c, false);
#else
  float2 fa = h2f2(a), fb = h2f2(b);
  return fmaf(fa.x, fb.x, fmaf(fa.y, fb.y, c));
#endif
}

// 24-deep software-pipelined dot: w strided by S (global), x2 in LDS. K%24==0.
template<int K, int S>
__device__ __forceinline__ float dotpipe(const unsigned* __restrict__ w,
                                         const unsigned* __restrict__ x2) {
  unsigned A[12], B[12];
  float acc[4] = {0.f, 0.f, 0.f, 0.f};
  #pragma unroll
  for (int i = 0; i < 12; ++i) A[i] = w[(size_t)i * S];
  #pragma unroll 1
  for (int k = 0; k < K; k += 24) {
    #pragma unroll
    for (int i = 0; i < 12; ++i) B[i] = w[(size_t)(k + 12 + i) * S];
    #pragma unroll
    for (int i = 0; i < 12; ++i) acc[i & 3] = fdot2f(A[i], x2[k + i], acc[i & 3]);
    if (k + 24 < K) {
      #pragma unroll
      for (int i = 0; i < 12; ++i) A[i] = w[(size_t)(k + 24 + i) * S];
    }
    #pragma unroll
    for (int i = 0; i < 12; ++i) acc[i & 3] = fdot2f(B[i], x2[k + 12 + i], acc[i & 3]);
  }
  return (acc[0] + acc[1]) + (acc[2] + acc[3]);
}

// ---------------- agent-scope atomics ----------------
__device__ __forceinline__ void ast(float* p, float v) {
  __hip_atomic_store(p, v, __ATOMIC_RELAXED, __HIP_MEMORY_SCOPE_AGENT);
}
__device__ __forceinline__ float ald(const float* p) {
  return __hip_atomic_load(p, __ATOMIC_RELAXED, __HIP_MEMORY_SCOPE_AGENT);
}
__device__ __forceinline__ void astu(unsigned* p, unsigned v) {
  __hip_atomic_store(p, v, __ATOMIC_RELAXED, __HIP_MEMORY_SCOPE_AGENT);
}
__device__ __forceinline__ unsigned aldu(const unsigned* p) {
  return __hip_atomic_load(p, __ATOMIC_RELAXED, __HIP_MEMORY_SCOPE_AGENT);
}
__device__ __forceinline__ void astull(unsigned long long* p, unsigned long long v) {
  __hip_atomic_store(p, v, __ATOMIC_RELAXED, __HIP_MEMORY_SCOPE_AGENT);
}
__device__ __forceinline__ unsigned long long aldull(const unsigned long long* p) {
  return __hip_atomic_load(p, __ATOMIC_RELAXED, __HIP_MEMORY_SCOPE_AGENT);
}
union F2U { unsigned long long u; float f[2]; };

// ---------------- precompute: proj (fp16 out, optional transpose / reversal) ----------------
struct ProjParams {
  const float* X[4]; const float* W[4]; __half* C[4]; int rev[4]; int transp[4];
};

__global__ __launch_bounds__(192) void proj_kernel(ProjParams pp) {
  __shared__ float xs[32 * 384];
  const int job = blockIdx.y;
  const float* __restrict__ X = pp.X[job];
  const float* __restrict__ W = pp.W[job];
  __half* __restrict__ C = pp.C[job];
  const int rev = pp.rev[job];
  const int transp = pp.transp[job];
  const int r0 = blockIdx.x * 32;
  const int tid = threadIdx.x;

  for (int idx = tid; idx < 32 * 384; idx += 192) {
    int r = idx / 384, k = idx - r * 384;
    int row = r0 + r;
    int srow = row;
    if (rev) { int t = row >> 6, b2 = row & 63; srow = ((TT - 1 - t) << 6) | b2; }
    xs[idx] = X[(size_t)srow * 384 + k];
  }
  __syncthreads();

  float acc[32];
  #pragma unroll
  for (int r = 0; r < 32; ++r) acc[r] = 0.f;
  for (int k = 0; k < 384; ++k) {
    float w = W[k * 192 + tid];
    #pragma unroll
    for (int r = 0; r < 32; ++r) acc[r] = fmaf(xs[r * 384 + k], w, acc[r]);
  }
  #pragma unroll
  for (int r = 0; r < 32; ++r) {
    int row = r0 + r;
    size_t di = transp ? (((size_t)(row & 63) * MM + (row >> 6)) * 192 + tid)
                       : ((size_t)row * 192 + tid);
    C[di] = __float2half(acc[r]);
  }
}

// memt[b][m][d] = half(memory[m][b][d])
__global__ __launch_bounds__(384) void memcvt_kernel(const float* __restrict__ src,
                                                     __half* __restrict__ dst) {
  int m = blockIdx.x, b = blockIdx.y, d = threadIdx.x;
  dst[((size_t)b * MM + m) * 384 + d] = __float2half(src[((size_t)m * 64 + b) * 384 + d]);
}

// k-pair interleaved fp16 weights: dst[k2*N+j] = pack(src[2k2][j], src[2k2+1][j])
struct WcvtParams { const float* src[8]; unsigned* dst[8]; int tot[8]; int N[8]; };
__global__ __launch_bounds__(256) void wcvt_kernel(WcvtParams wp) {
  int job = blockIdx.y;
  const float* __restrict__ s = wp.src[job];
  unsigned* __restrict__ d = wp.dst[job];
  int n = wp.N[job], tot = wp.tot[job];
  for (int i = blockIdx.x * 256 + threadIdx.x; i < tot; i += gridDim.x * 256) {
    int k2 = i / n, j = i - k2 * n;
    d[i] = pack2(s[(size_t)(2 * k2) * n + j], s[(size_t)(2 * k2 + 1) * n + j]);
  }
}

// ---------------- LDS layout (bytes) ----------------
#define L_MP     0         // 256*192 halfs = 98304
#define L_REDP   98304     // 8*384 f = 12288
#define L_SH384  110592    // q-parts / ctx-mine / raw g overlay: 384 f
#define L_Q      112128    // 192 f
#define L_XCF    112896    // 768 f
#define L_XC2    115968    // 384 u
#define L_G2     117504    // 384 u
#define L_GIS    119040    // 288 f
#define L_GHS    120192    // 288 f
#define L_HF     121344    // 192 f
#define L_H2     122112    // 96 u
#define L_VS     122496    // 192 f
#define L_BIH    123264    // 288 f
#define L_BHH    124416    // 288 f
#define L_ZP     125568    // 8 f
#define L_MISC   125600    // 8 f
#define L_ES     125632    // 256 f = 1024
#define SCAN_LDS 126656
static_assert(SCAN_LDS <= 160 * 1024, "LDS overflow");

struct ScanParams {
  const float* input;        // [512][64][384] f32
  const unsigned* memt;      // [64][512][192] u (384 halfs)
  const unsigned* mpt[2];    // [64][512][96] u (192 halfs)
  const __half* xp[2];       // [512][64][192] half
  const unsigned* Wh2[2];    // [96][192] u
  const unsigned* Wg2[2];    // [384][768] u
  const unsigned* Wih2[2];   // [384][576] u
  const unsigned* Whh2[2];   // [96][576] u
  const float* v[2];
  const float* bih[2];
  const float* bhh[2];
  unsigned long long* ectx;  // [dirhalf][b][2 par][192] f32-pairs
  float* ez;                 // [dirhalf][b][2 par]
  unsigned* gmail;           // [dirhalf][b][2 par][192] packed half2
  unsigned* hmail;           // [dirhalf][b][2 par][48] packed half2
  unsigned* flags;           // 3 arrays x [dirhalf][b]
  float* out;                // [512][64][384]
};

__global__ __launch_bounds__(512, 1) void scan_kernel(ScanParams p) {
  extern __shared__ char smem[];
  __half*   mp_s   = (__half*)(smem + L_MP);
  float*    redp   = (float*)(smem + L_REDP);
  float*    sh384  = (float*)(smem + L_SH384);
  float*    q_s    = (float*)(smem + L_Q);
  float*    xc_f   = (float*)(smem + L_XCF);
  unsigned* xc2_s  = (unsigned*)(smem + L_XC2);
  unsigned* g2_s   = (unsigned*)(smem + L_G2);
  float*    gis    = (float*)(smem + L_GIS);
  float*    ghs    = (float*)(smem + L_GHS);
  float*    h_f    = (float*)(smem + L_HF);
  unsigned* h2_s   = (unsigned*)(smem + L_H2);
  float*    v_s    = (float*)(smem + L_VS);
  float*    bih_s  = (float*)(smem + L_BIH);
  float*    bhh_s  = (float*)(smem + L_BHH);
  float*    zp_s   = (float*)(smem + L_ZP);
  float*    e_s    = (float*)(smem + L_ES);

  // XCD-grouped mapping: xcd 0-3 -> dir0, 4-7 -> dir1
  const int g = blockIdx.x;
  const int xcd = g & 7;
  const int slot = g >> 3;
  const int dir = xcd >> 2;
  const int idx = (xcd & 3) * 32 + slot;   // 0..127
  const int b = idx & 63;
  const int half = idx >> 6;
  const int tid = threadIdx.x;
  const int lane = tid & 63;
  const int wv = tid >> 6;

  const unsigned* __restrict__ Wh2  = p.Wh2[dir];
  const unsigned* __restrict__ Wg2  = p.Wg2[dir];
  const unsigned* __restrict__ Wih2 = p.Wih2[dir];
  const unsigned* __restrict__ Whh2 = p.Whh2[dir];
  const __half* __restrict__ xp = p.xp[dir];
  const int m0 = half * 256;

  const int idx_my = (dir * 2 + half) * 64 + b;
  const int idx_p  = (dir * 2 + (half ^ 1)) * 64 + b;
  unsigned long long* myctx_u = p.ectx + (size_t)idx_my * 2 * 192;
  const unsigned long long* pctx_u = p.ectx + (size_t)idx_p * 2 * 192;
  float* myz0 = p.ez + (size_t)idx_my * 2;
  const float* pz0 = p.ez + (size_t)idx_p * 2;
  unsigned* gmail_my = p.gmail + (size_t)idx_my * 2 * 192;
  const unsigned* gmail_p = p.gmail + (size_t)idx_p * 2 * 192;
  unsigned* hmail_my = p.hmail + (size_t)idx_my * 2 * 48;
  const unsigned* hmail_p = p.hmail + (size_t)idx_p * 2 * 48;
  unsigned* fctx_my = p.flags + idx_my;        const unsigned* fctx_p = p.flags + idx_p;
  unsigned* fg_my   = p.flags + 256 + idx_my;  const unsigned* fg_p   = p.flags + 256 + idx_p;
  unsigned* fh_my   = p.flags + 512 + idx_my;  const unsigned* fh_p   = p.flags + 512 + idx_p;

  // ---- init ----
  {
    const unsigned* mpu = p.mpt[dir] + ((size_t)b * MM + m0) * 96;
    unsigned* mpd = (unsigned*)mp_s;
    for (int i = tid; i < 256 * 96; i += 512) mpd[i] = mpu[i];
    if (tid < 192) { h_f[tid] = 0.f; v_s[tid] = p.v[dir][tid]; }
    if (tid < 96) h2_s[tid] = 0u;
    if (tid < 288) {
      int c3 = tid / 96, jj = tid - c3 * 96;
      int col = c3 * 192 + 96 * half + jj;
      bih_s[tid] = p.bih[dir][col];
      bhh_s[tid] = p.bhh[dir][col];
    }
  }
  __syncthreads();
  const float v0 = v_s[lane], v1 = v_s[lane + 64], v2 = v_s[lane + 128];

  #pragma unroll 1
  for (int t = 0; t < TT; ++t) {
    const int par = t & 1;
    // ---- A: q = xp[t,b,:] + h @ Wh ----
    if (tid < 384) {
      const int kh = (tid >= 192);
      const int a = tid - 192 * kh;
      sh384[tid] = dotpipe<48, 192>(Wh2 + (size_t)kh * 48 * 192 + a, h2_s + kh * 48);
    }
    __syncthreads();
    if (tid < 192)
      q_s[tid] = __half2float(xp[((size_t)t * 64 + b) * 192 + tid]) + sh384[tid] + sh384[192 + tid];
    __syncthreads();

    // ---- B1: scores for my 256 rows -> e_s, per-wave Z ----
    {
      const float q0 = q_s[lane], q1 = q_s[lane + 64], q2 = q_s[lane + 128];
      float zacc = 0.f;
      const __half* mph = mp_s + (wv * 32) * 192;
      #pragma unroll 4
      for (int i = 0; i < 32; ++i) {
        const __half* r = mph + i * 192;
        float s = v0 * fast_tanh(__half2float(r[lane]) + q0)
                + v1 * fast_tanh(__half2float(r[lane + 64]) + q1)
                + v2 * fast_tanh(__half2float(r[lane + 128]) + q2);
        #pragma unroll
        for (int off = 32; off > 0; off >>= 1) s += __shfl_xor(s, off, 64);
        float e = __expf(s);
        zacc += e;
        if (lane == 0) e_s[wv * 32 + i] = e;
      }
      if (lane == 0) zp_s[wv] = zacc;
    }
    __syncthreads();
    // ---- B2: context, uint4 loads (16B/slot), lanes 0-47, unroll 8 ----
    {
      float ca[8] = {0, 0, 0, 0, 0, 0, 0, 0};
      if (lane < 48) {
        const uint4* mrow4 = (const uint4*)(p.memt + ((size_t)b * MM + m0 + wv * 32) * 192) + lane;
        const float* es = e_s + wv * 32;
        #pragma unroll 8
        for (int i = 0; i < 32; ++i) {
          uint4 mv = mrow4[(size_t)i * 48];
          float e = es[i];
          float2 f0 = h2f2(mv.x), f1 = h2f2(mv.y), f2 = h2f2(mv.z), f3 = h2f2(mv.w);
          ca[0] = fmaf(e, f0.x, ca[0]); ca[1] = fmaf(e, f0.y, ca[1]);
          ca[2] = fmaf(e, f1.x, ca[2]); ca[3] = fmaf(e, f1.y, ca[3]);
          ca[4] = fmaf(e, f2.x, ca[4]); ca[5] = fmaf(e, f2.y, ca[5]);
          ca[6] = fmaf(e, f3.x, ca[6]); ca[7] = fmaf(e, f3.y, ca[7]);
        }
        float2* rp2 = (float2*)(redp + wv * 384 + 8 * lane);
        rp2[0] = make_float2(ca[0], ca[1]);
        rp2[1] = make_float2(ca[2], ca[3]);
        rp2[2] = make_float2(ca[4], ca[5]);
        rp2[3] = make_float2(ca[6], ca[7]);
      }
    }
    __syncthreads();

    // ---- C: combine partials -> mailbox; input row load + pack (same threads) ----
    const int xt = dir ? (TT - 1 - t) : t;
    const float* xrow = p.input + ((size_t)xt * 64 + b) * 384;
    if (tid < 192) {
      float cm0 = 0.f, cm1 = 0.f;
      const float2* rp2 = (const float2*)redp;
      #pragma unroll
      for (int k = 0; k < 8; ++k) {
        float2 v2r = rp2[k * 192 + tid];
        cm0 += v2r.x; cm1 += v2r.y;
      }
      sh384[2 * tid] = cm0; sh384[2 * tid + 1] = cm1;
      F2U u; u.f[0] = cm0; u.f[1] = cm1;
      astull(myctx_u + par * 192 + tid, u.u);
      float2 xi = ((const float2*)xrow)[tid];
      xc_f[2 * tid] = xi.x; xc_f[2 * tid + 1] = xi.y;
      xc2_s[tid] = pack2(xi.x, xi.y);
    }
    if (tid == 0) {
      float zs = 0.f;
      #pragma unroll
      for (int k = 0; k < 8; ++k) zs += zp_s[k];
      ast(myz0 + par, zs);
    }
    __syncthreads();   // drains mailbox stores; xc2 input half visible
    if (tid == 0) astu(fctx_my, (unsigned)(t + 1));

    // ---- E1: gate partial over input half; ghs on waves 6-7; then D (poll hidden) ----
    float eacc = 0.f;
    if (tid < 384) {
      const int col = 384 * half + tid;
      eacc = dotpipe<192, 768>(Wg2 + col, xc2_s);
    } else {
      for (int jj = tid - 384; jj < 288; jj += 128) {
        const int c3 = jj / 96;
        const int col = c3 * 192 + 96 * half + (jj - c3 * 96);
        ghs[jj] = dotpipe<96, 576>(Whh2 + col, h2_s) + bhh_s[jj];
      }
    }
    // ---- D: per-thread poll + partner ctx read + xc ctx-half build ----
    if (tid < 192) {
      while (aldu(fctx_p) < (unsigned)(t + 1)) __builtin_amdgcn_s_sleep(1);
      F2U u; u.u = aldull(pctx_u + par * 192 + tid);
      float zl = ((zp_s[0] + zp_s[1]) + (zp_s[2] + zp_s[3]))
               + ((zp_s[4] + zp_s[5]) + (zp_s[6] + zp_s[7]));
      float pz = ald(pz0 + par);
      float iz = __builtin_amdgcn_rcpf(zl + pz);
      float x0 = (sh384[2 * tid] + u.f[0]) * iz;
      float x1 = (sh384[2 * tid + 1] + u.f[1]) * iz;
      xc_f[384 + 2 * tid] = x0;
      xc_f[384 + 2 * tid + 1] = x1;
      xc2_s[192 + tid] = pack2(x0, x1);
    }
    __syncthreads();

    // ---- E2: finish gate ----
    if (tid < 384) {
      const int col = 384 * half + tid;
      eacc += dotpipe<192, 768>(Wg2 + (size_t)192 * 768 + col, xc2_s + 192);
      sh384[tid] = fast_sigmoid(eacc) * xc_f[col];
    }
    __syncthreads();

    // ---- g mailbox ----
    if (tid < 192) {
      unsigned pk = pack2(sh384[2 * tid], sh384[2 * tid + 1]);
      g2_s[192 * half + tid] = pk;
      astu(gmail_my + par * 192 + tid, pk);
    }
    __syncthreads();   // drain mailbox stores; g2 own half visible
    if (tid == 0) astu(fg_my, (unsigned)(t + 1));

    // ---- G1: gi partial over my g half; then F (poll hidden behind G1) ----
    float gacc = 0.f;
    if (tid < 288) {
      const int c3 = tid / 96, jj = tid - c3 * 96;
      const int col = c3 * 192 + 96 * half + jj;
      gacc = dotpipe<192, 576>(Wih2 + (size_t)(192 * half) * 576 + col, g2_s + 192 * half);
    }
    if (tid < 192) {
      while (aldu(fg_p) < (unsigned)(t + 1)) __builtin_amdgcn_s_sleep(1);
      g2_s[192 * (1 - half) + tid] = aldu(gmail_p + par * 192 + tid);
    }
    __syncthreads();

    // ---- G2: finish gi ----
    if (tid < 288) {
      const int c3 = tid / 96, jj = tid - c3 * 96;
      const int col = c3 * 192 + 96 * half + jj;
      gis[tid] = gacc + bih_s[tid]
               + dotpipe<192, 576>(Wih2 + (size_t)(192 * (1 - half)) * 576 + col,
                                   g2_s + 192 * (1 - half));
    }
    __syncthreads();

    // ---- H: GRU update, 2 cols/thread (update + pack + mailbox in one block) ----
    if (tid < 48) {
      const int j0 = 96 * half + 2 * tid;
      float r0 = fast_sigmoid(gis[2 * tid]       + ghs[2 * tid]);
      float z0 = fast_sigmoid(gis[96 + 2 * tid]  + ghs[96 + 2 * tid]);
      float n0 = fast_tanh(gis[192 + 2 * tid] + r0 * ghs[192 + 2 * tid]);
      float hn0 = (1.f - z0) * n0 + z0 * h_f[j0];
      float r1 = fast_sigmoid(gis[2 * tid + 1]      + ghs[2 * tid + 1]);
      float z1 = fast_sigmoid(gis[96 + 2 * tid + 1] + ghs[96 + 2 * tid + 1]);
      float n1 = fast_tanh(gis[192 + 2 * tid + 1] + r1 * ghs[192 + 2 * tid + 1]);
      float hn1 = (1.f - z1) * n1 + z1 * h_f[j0 + 1];
      h_f[j0] = hn0; h_f[j0 + 1] = hn1;
      int trow = dir ? (TT - 1 - t) : t;
      float2* orow = (float2*)(p.out + ((size_t)trow * 64 + b) * 384 + dir * 192);
      orow[48 * half + tid] = make_float2(hn0, hn1);
      unsigned pk = pack2(hn0, hn1);
      h2_s[48 * half + tid] = pk;
      astu(hmail_my + par * 48 + tid, pk);
    }
    __syncthreads();   // drain
    if (tid == 0) astu(fh_my, (unsigned)(t + 1));
    if (tid < 48) {
      while (aldu(fh_p) < (unsigned)(t + 1)) __builtin_amdgcn_s_sleep(1);
      h2_s[48 * (1 - half) + tid] = aldu(hmail_p + par * 48 + tid);
    }
    __syncthreads();
  }
}

// ---------------- launcher ----------------
extern "C" void kernel_launch(void* const* d_in, const int* in_sizes, int n_in,
                              void* d_out, int out_size, void* d_ws, size_t ws_size,
                              hipStream_t stream) {
  (void)in_sizes; (void)n_in; (void)out_size;
  const float* memory = (const float*)d_in[0];
  const float* input  = (const float*)d_in[2];
  const float* Wm[2]  = {(const float*)d_in[3],  (const float*)d_in[12]};
  const float* Wx[2]  = {(const float*)d_in[4],  (const float*)d_in[13]};
  const float* Wh[2]  = {(const float*)d_in[5],  (const float*)d_in[14]};
  const float* v[2]   = {(const float*)d_in[6],  (const float*)d_in[15]};
  const float* Wg[2]  = {(const float*)d_in[7],  (const float*)d_in[16]};
  const float* Wih[2] = {(const float*)d_in[8],  (const float*)d_in[17]};
  const float* Whh[2] = {(const float*)d_in[9],  (const float*)d_in[18]};
  const float* bih[2] = {(const float*)d_in[10], (const float*)d_in[19]};
  const float* bhh[2] = {(const float*)d_in[11], (const float*)d_in[20]};

  char* ws = (char*)d_ws;
  const size_t OFF_FLAGS = 0;         // 4096 (3 flag arrays x 256 u32)
  const size_t OFF_EZ    = 4096;      // 2048
  const size_t OFF_GMAIL = 6144;      // 786432
  const size_t OFF_HMAIL = 792576;    // 196608
  const size_t OFF_ECTX  = 989184;    // 786432
  const size_t OFF_MPT0  = 1775616;
  const size_t OFF_MPT1  = OFF_MPT0 + 12582912;
  const size_t OFF_XP0   = OFF_MPT1 + 12582912;
  const size_t OFF_XP1   = OFF_XP0 + 12582912;
  const size_t OFF_MT    = OFF_XP1 + 12582912;
  const size_t OFF_WG0   = OFF_MT + 25165824;
  const size_t OFF_WG1   = OFF_WG0 + 1179648;
  const size_t OFF_WIH0  = OFF_WG1 + 1179648;
  const size_t OFF_WIH1  = OFF_WIH0 + 884736;
  const size_t OFF_WHH0  = OFF_WIH1 + 884736;
  const size_t OFF_WHH1  = OFF_WHH0 + 221184;
  const size_t OFF_WH0   = OFF_WHH1 + 221184;
  const size_t OFF_WH1   = OFF_WH0 + 73728;
  const size_t NEEDED    = OFF_WH1 + 73728;   // ~82 MB
  if (ws_size < NEEDED) return;

  unsigned* flags = (unsigned*)(ws + OFF_FLAGS);
  float* ez    = (float*)(ws + OFF_EZ);
  unsigned* gmail = (unsigned*)(ws + OFF_GMAIL);
  unsigned* hmail = (unsigned*)(ws + OFF_HMAIL);
  unsigned long long* ectx = (unsigned long long*)(ws + OFF_ECTX);
  __half* mpt0 = (__half*)(ws + OFF_MPT0);
  __half* mpt1 = (__half*)(ws + OFF_MPT1);
  __half* xp0  = (__half*)(ws + OFF_XP0);
  __half* xp1  = (__half*)(ws + OFF_XP1);
  __half* memt = (__half*)(ws + OFF_MT);
  unsigned* wg2[2]  = {(unsigned*)(ws + OFF_WG0),  (unsigned*)(ws + OFF_WG1)};
  unsigned* wih2[2] = {(unsigned*)(ws + OFF_WIH0), (unsigned*)(ws + OFF_WIH1)};
  unsigned* whh2[2] = {(unsigned*)(ws + OFF_WHH0), (unsigned*)(ws + OFF_WHH1)};
  unsigned* wh2[2]  = {(unsigned*)(ws + OFF_WH0),  (unsigned*)(ws + OFF_WH1)};

  hipFuncSetAttribute(reinterpret_cast<const void*>(scan_kernel),
                      hipFuncAttributeMaxDynamicSharedMemorySize, SCAN_LDS);

  hipMemsetAsync(ws + OFF_FLAGS, 0, 4096, stream);   // flags only

  ProjParams pp;
  pp.X[0] = memory; pp.W[0] = Wm[0]; pp.C[0] = mpt0; pp.rev[0] = 0; pp.transp[0] = 1;
  pp.X[1] = memory; pp.W[1] = Wm[1]; pp.C[1] = mpt1; pp.rev[1] = 0; pp.transp[1] = 1;
  pp.X[2] = input;  pp.W[2] = Wx[0]; pp.C[2] = xp0;  pp.rev[2] = 0; pp.transp[2] = 0;
  pp.X[3] = input;  pp.W[3] = Wx[1]; pp.C[3] = xp1;  pp.rev[3] = 1; pp.transp[3] = 0;
  proj_kernel<<<dim3(1024, 4), dim3(192), 0, stream>>>(pp);
  memcvt_kernel<<<dim3(MM, 64), dim3(384), 0, stream>>>(memory, memt);

  WcvtParams wp;
  for (int d = 0; d < 2; ++d) {
    wp.src[d]     = Wg[d];  wp.dst[d]     = wg2[d];  wp.tot[d]     = 384 * 768; wp.N[d]     = 768;
    wp.src[2 + d] = Wih[d]; wp.dst[2 + d] = wih2[d]; wp.tot[2 + d] = 384 * 576; wp.N[2 + d] = 576;
    wp.src[4 + d] = Whh[d]; wp.dst[4 + d] = whh2[d]; wp.tot[4 + d] = 96 * 576;  wp.N[4 + d] = 576;
    wp.src[6 + d] = Wh[d];  wp.dst[6 + d] = wh2[d];  wp.tot[6 + d] = 96 * 192;  wp.N[6 + d] = 192;
  }
  wcvt_kernel<<<dim3(288, 8), dim3(256), 0, stream>>>(wp);

  ScanParams sp;
  sp.input = input;
  sp.memt = (const unsigned*)memt;
  sp.mpt[0] = (const unsigned*)mpt0; sp.mpt[1] = (const unsigned*)mpt1;
  sp.xp[0] = xp0; sp.xp[1] = xp1;
  for (int d = 0; d < 2; ++d) {
    sp.Wh2[d] = wh2[d]; sp.Wg2[d] = wg2[d]; sp.Wih2[d] = wih2[d]; sp.Whh2[d] = whh2[d];
    sp.v[d] = v[d]; sp.bih[d] = bih[d]; sp.bhh[d] = bhh[d];
  }
  sp.ectx = ectx; sp.ez = ez; sp.gmail = gmail; sp.hmail = hmail; sp.flags = flags;
  sp.out = (float*)d_out;
  scan_kernel<<<dim3(NWG), dim3(512), SCAN_LDS, stream>>>(sp);
}